// Round 10
// baseline (363.455 us; speedup 1.0000x reference)
//
#include <hip/hip_runtime.h>
#include <hip/hip_bf16.h>
#include <math.h>

// pk row: 256 bf16 = 512B, line-aligned.
//   elems 0..127  : E0E1 region, chunk c (0..15) = [e0[4c..4c+3] | e1[4c..4c+3]]
//   elems 128..255: Y2XT region, chunk c = [y2 quad | xt quad]
// e2 lives in a separate dense e2b[N][64] (never gathered).
#define PK_STRIDE 256
#define LDA 72       // LDS row stride (bf16 elems)
#define TSHIFT 13    // t-bucket = t >> TSHIFT (8192 nodes = 4.2MB pk per bucket)

typedef float v4f __attribute__((ext_vector_type(4)));
typedef __attribute__((ext_vector_type(8))) short s8;
typedef __attribute__((ext_vector_type(4))) float f4;

__device__ __forceinline__ float4 f4z() { return make_float4(0.f, 0.f, 0.f, 0.f); }
__device__ __forceinline__ void fma4(float4& a, float s, const float4& v) {
  a.x = fmaf(s, v.x, a.x); a.y = fmaf(s, v.y, a.y);
  a.z = fmaf(s, v.z, a.z); a.w = fmaf(s, v.w, a.w);
}
__device__ __forceinline__ float4 add4(const float4& a, const float4& b) {
  return make_float4(a.x + b.x, a.y + b.y, a.z + b.z, a.w + b.w);
}
__device__ __forceinline__ void stnt4(float* p, const float4& v) {
  v4f u; u.x = v.x; u.y = v.y; u.z = v.z; u.w = v.w;
  __builtin_nontemporal_store(u, (v4f*)p);
}
__device__ __forceinline__ float4 lo4(const uint4& u) {
  float4 f;
  f.x = __uint_as_float(u.x << 16);
  f.y = __uint_as_float(u.x & 0xffff0000u);
  f.z = __uint_as_float(u.y << 16);
  f.w = __uint_as_float(u.y & 0xffff0000u);
  return f;
}
__device__ __forceinline__ float4 hi4(const uint4& u) {
  float4 f;
  f.x = __uint_as_float(u.z << 16);
  f.y = __uint_as_float(u.z & 0xffff0000u);
  f.z = __uint_as_float(u.w << 16);
  f.w = __uint_as_float(u.w & 0xffff0000u);
  return f;
}
__device__ __forceinline__ float4 ldbf4(const unsigned short* p) {
  ushort4 u = *(const ushort4*)p;
  float4 f;
  f.x = __uint_as_float((unsigned)u.x << 16);
  f.y = __uint_as_float((unsigned)u.y << 16);
  f.z = __uint_as_float((unsigned)u.z << 16);
  f.w = __uint_as_float((unsigned)u.w << 16);
  return f;
}
__device__ __forceinline__ unsigned short f2bf(float v) {
  __hip_bfloat16 h = __float2bfloat16(v);
  return *reinterpret_cast<unsigned short*>(&h);
}
__device__ __forceinline__ unsigned pack2(float a, float b) {
  return ((unsigned)f2bf(b) << 16) | (unsigned)f2bf(a);
}
__device__ __forceinline__ void st4bf(unsigned short* p, const float4& v) {
  ushort4 u;
  u.x = f2bf(v.x); u.y = f2bf(v.y); u.z = f2bf(v.z); u.w = f2bf(v.w);
  *(ushort4*)p = u;
}
__device__ __forceinline__ float fsig(float x) {
  return __builtin_amdgcn_rcpf(1.f + __expf(-x));
}

// -------- init: pk0 E0E1 = [emb0|emb0]; e2b = emb0 --------
__global__ void init_k(const float* __restrict__ emb0, unsigned short* __restrict__ pk0,
                       unsigned short* __restrict__ e2b, int N) {
  int idx = blockIdx.x * blockDim.x + threadIdx.x;
  int n = idx >> 4, q = idx & 15;
  if (n >= N) return;
  float4 v = *(const float4*)(emb0 + (size_t)n * 64 + q * 4);
  unsigned p01 = pack2(v.x, v.y), p23 = pack2(v.z, v.w);
  uint4 u = make_uint4(p01, p23, p01, p23);
  *(uint4*)(pk0 + (size_t)n * PK_STRIDE + q * 8) = u;
  st4bf(e2b + (size_t)n * 64 + q * 4, v);
}

// ---------------- bucketed CSR build over N*B bins keyed (h, t>>TSHIFT) ------
__global__ void hist_k(const int* __restrict__ h, const int* __restrict__ t,
                       int* __restrict__ deg, int E, int B) {
  int i = blockIdx.x * blockDim.x + threadIdx.x;
  if (i < E) atomicAdd(&deg[(size_t)h[i] * B + ((unsigned)t[i] >> TSHIFT)], 1);
}

__global__ void scanA_k(const int* __restrict__ deg, int* __restrict__ rp,
                        int* __restrict__ sums, int NB) {
  __shared__ int s[1024];
  int i = blockIdx.x * 1024 + threadIdx.x;
  int v = (i < NB) ? deg[i] : 0;
  s[threadIdx.x] = v;
  __syncthreads();
  for (int off = 1; off < 1024; off <<= 1) {
    int t = (threadIdx.x >= (unsigned)off) ? s[threadIdx.x - off] : 0;
    __syncthreads();
    s[threadIdx.x] += t;
    __syncthreads();
  }
  if (i < NB) rp[i] = s[threadIdx.x] - v;
  if (threadIdx.x == 1023) sums[blockIdx.x] = s[1023];
}

__global__ void scanB_k(int* sums, int nch) {
  int lane = threadIdx.x;   // 64 threads
  int run = 0;
  for (int base = 0; base < nch; base += 64) {
    int v = (base + lane < nch) ? sums[base + lane] : 0;
    int incl = v;
    for (int off = 1; off < 64; off <<= 1) {
      int t = __shfl_up(incl, off, 64);
      if (lane >= off) incl += t;
    }
    if (base + lane < nch) sums[base + lane] = run + (incl - v);
    run += __shfl(incl, 63, 64);
  }
}

__global__ void scanC_k(int* __restrict__ rp, int* __restrict__ cur,
                        const int* __restrict__ sums, int NB, int E) {
  int i = blockIdx.x * blockDim.x + threadIdx.x;
  if (i < NB) {
    int v = rp[i] + sums[i >> 10];
    rp[i] = v; cur[i] = v;
  } else if (i == NB) {
    rp[NB] = E;
  }
}

// fill: one 16B emeta write per edge {toff, G, gum_l0, gum_l1}; cgum only if L>2
__global__ void fill_k(const int* __restrict__ h, const int* __restrict__ t_idx,
                       const float* __restrict__ G, const float* __restrict__ gum,
                       int* __restrict__ cur, int4* __restrict__ emeta,
                       float* __restrict__ cgum, int E, int L, int B) {
  int i = blockIdx.x * blockDim.x + threadIdx.x;
  if (i < E) {
    int t = t_idx[i];
    int pos = atomicAdd(&cur[(size_t)h[i] * B + ((unsigned)t >> TSHIFT)], 1);
    int4 em;
    em.x = t * PK_STRIDE;
    em.y = __float_as_int(G[i]);
    em.z = __float_as_int(gum[i]);
    em.w = (L > 1) ? __float_as_int(gum[(size_t)E + i]) : 0;
    emeta[pos] = em;
    if (L > 2)
      for (int l = 2; l < L; l++) cgum[(size_t)l * E + pos] = gum[(size_t)l * E + i];
  }
}

// ------- weight prep: transpose + bf16 once -------
__global__ void wprep_k(const float* __restrict__ edge_W1,
                        const float* __restrict__ emb_W1,
                        const float* __restrict__ emb_W2,
                        unsigned short* __restrict__ wxT,
                        unsigned short* __restrict__ w1T,
                        unsigned short* __restrict__ w2T, int L) {
  const int per = 128 * 64 + 64 * 64 + 64 * 64;   // 16384
  int i = blockIdx.x * blockDim.x + threadIdx.x;
  if (i >= L * per) return;
  int layer = i / per, r = i % per;
  if (r < 8192) {
    int j = r >> 6, k = r & 63;
    float v = (j < 64) ? edge_W1[((size_t)layer * 128 + k) * 64 + j]
                       : edge_W1[((size_t)layer * 128 + 64 + k) * 64 + (j - 64)];
    wxT[(size_t)layer * 8192 + j * 64 + k] = f2bf(v);
  } else if (r < 8192 + 4096) {
    int q = r - 8192; int n = q >> 6, k = q & 63;
    w1T[(size_t)layer * 4096 + n * 64 + k] =
        f2bf(emb_W1[((size_t)layer * 64 + k) * 64 + n]);
  } else {
    int q = r - 12288; int n = q >> 6, k = q & 63;
    w2T[(size_t)layer * 4096 + n * 64 + k] =
        f2bf(emb_W2[((size_t)layer * 64 + k) * 64 + n]);
  }
}

// ------- fused dense layer (MFMA) -------
__global__ __launch_bounds__(256) void dense_k(
    const unsigned short* __restrict__ pkin,   // e1 source (E0E1 hi quads)
    const unsigned short* __restrict__ e2b,
    const unsigned short* __restrict__ wxT,    // [128][64] bf16
    const unsigned short* __restrict__ w1T,    // [64][64]
    const unsigned short* __restrict__ w2T,    // [64][64]
    const float* __restrict__ b1,
    const float* __restrict__ b2,
    const float* __restrict__ gum,
    unsigned short* __restrict__ xhb,
    unsigned short* __restrict__ pk,
    int N) {
  __shared__ unsigned short a1[64 * LDA];      // e1, reused as ht
  __shared__ unsigned short a2[64 * LDA];      // e2
  __shared__ unsigned short wx[128 * LDA];
  __shared__ unsigned short w1[64 * LDA];
  __shared__ unsigned short w2[64 * LDA];
  int tid = threadIdx.x;
  int n0 = blockIdx.x * 64;
  for (int i = tid; i < 64 * 16; i += 256) {
    int r = i >> 4, c = i & 15;
    ushort4 v1 = make_ushort4(0, 0, 0, 0), v2 = v1;
    if (n0 + r < N) {
      v1 = *(const ushort4*)(pkin + (size_t)(n0 + r) * PK_STRIDE + c * 8 + 4);
      v2 = *(const ushort4*)(e2b + (size_t)(n0 + r) * 64 + c * 4);
    }
    *(ushort4*)(a1 + r * LDA + c * 4) = v1;
    *(ushort4*)(a2 + r * LDA + c * 4) = v2;
  }
  for (int i = tid; i < 128 * 8; i += 256) {
    int r = i >> 3, s = i & 7;
    *(uint4*)(wx + r * LDA + s * 8) = *(const uint4*)(wxT + r * 64 + s * 8);
  }
  for (int i = tid; i < 64 * 8; i += 256) {
    int r = i >> 3, s = i & 7;
    *(uint4*)(w1 + r * LDA + s * 8) = *(const uint4*)(w1T + r * 64 + s * 8);
    *(uint4*)(w2 + r * LDA + s * 8) = *(const uint4*)(w2T + r * 64 + s * 8);
  }
  __syncthreads();
  int wv = tid >> 6, l = tid & 63;
  int l15 = l & 15, lg = l >> 4;
  int wr = wv * 16;
  int arow = wr + l15;
  s8 af1_0 = *(const s8*)(a1 + arow * LDA + 8 * lg);
  s8 af1_1 = *(const s8*)(a1 + arow * LDA + 32 + 8 * lg);
#pragma unroll
  for (int ct = 0; ct < 8; ct++) {
    f4 acc = {0.f, 0.f, 0.f, 0.f};
    s8 b0 = *(const s8*)(wx + (ct * 16 + l15) * LDA + 8 * lg);
    s8 bI = *(const s8*)(wx + (ct * 16 + l15) * LDA + 32 + 8 * lg);
    acc = __builtin_amdgcn_mfma_f32_16x16x32_bf16(af1_0, b0, acc, 0, 0, 0);
    acc = __builtin_amdgcn_mfma_f32_16x16x32_bf16(af1_1, bI, acc, 0, 0, 0);
#pragma unroll
    for (int j = 0; j < 4; j++) {
      int n = n0 + wr + lg * 4 + j;
      if (n < N) {
        if (ct < 4) {
          xhb[(size_t)n * 64 + ct * 16 + l15] = f2bf(acc[j]);
        } else {
          int c2 = (ct - 4) * 16 + l15;
          pk[(size_t)n * PK_STRIDE + 128 + (c2 >> 2) * 8 + 4 + (c2 & 3)] = f2bf(acc[j]);
        }
      }
    }
  }
  s8 af2_0 = *(const s8*)(a2 + arow * LDA + 8 * lg);
  s8 af2_1 = *(const s8*)(a2 + arow * LDA + 32 + 8 * lg);
#pragma unroll
  for (int ct = 0; ct < 4; ct++) {
    f4 acc = {0.f, 0.f, 0.f, 0.f};
    s8 b0 = *(const s8*)(w1 + (ct * 16 + l15) * LDA + 8 * lg);
    s8 bI = *(const s8*)(w1 + (ct * 16 + l15) * LDA + 32 + 8 * lg);
    acc = __builtin_amdgcn_mfma_f32_16x16x32_bf16(af2_0, b0, acc, 0, 0, 0);
    acc = __builtin_amdgcn_mfma_f32_16x16x32_bf16(af2_1, bI, acc, 0, 0, 0);
    float bb = b1[ct * 16 + l15];
#pragma unroll
    for (int j = 0; j < 4; j++) {
      float h = fmaxf(acc[j] + bb, 0.f);
      a1[(wr + lg * 4 + j) * LDA + ct * 16 + l15] = f2bf(h);
    }
  }
  s8 afh_0 = *(const s8*)(a1 + arow * LDA + 8 * lg);
  s8 afh_1 = *(const s8*)(a1 + arow * LDA + 32 + 8 * lg);
#pragma unroll
  for (int ct = 0; ct < 4; ct++) {
    f4 acc = {0.f, 0.f, 0.f, 0.f};
    s8 b0 = *(const s8*)(w2 + (ct * 16 + l15) * LDA + 8 * lg);
    s8 bI = *(const s8*)(w2 + (ct * 16 + l15) * LDA + 32 + 8 * lg);
    acc = __builtin_amdgcn_mfma_f32_16x16x32_bf16(afh_0, b0, acc, 0, 0, 0);
    acc = __builtin_amdgcn_mfma_f32_16x16x32_bf16(afh_1, bI, acc, 0, 0, 0);
    int c2 = ct * 16 + l15;
    float bb = b2[c2];
#pragma unroll
    for (int j = 0; j < 4; j++) {
      int row = wr + lg * 4 + j;
      int n = n0 + row;
      if (n < N) {
        float gv = gum[(size_t)n * 64 + c2];
        float e2v = __uint_as_float((unsigned)a2[row * LDA + c2] << 16);
        float y = e2v * fsig(gv + acc[j] + bb);
        pk[(size_t)n * PK_STRIDE + 128 + (c2 >> 2) * 8 + (c2 & 3)] = f2bf(y);
      }
    }
  }
}

// ------- fused 3-branch SpMM + edge-MLP + dinv + residual + out -------
#define CH 2

#define LOADCH(Abuf, Bbuf, I0)                                          \
  _Pragma("unroll")                                                     \
  for (int c = 0; c < CH; c++) {                                        \
    int i_ = (I0) + c;                                                  \
    int tof_ = __shfl(em.x, i_ & 15, 16);                               \
    if (i_ < cnt) {                                                     \
      const unsigned short* pr_ = pk + (size_t)tof_ + l * 8;            \
      Abuf[c] = *(const uint4*)(pr_);                                   \
      Bbuf[c] = *(const uint4*)(pr_ + 128);                             \
    }                                                                   \
  }

#define COMPCH(Abuf, Bbuf, I0)                                          \
  _Pragma("unroll")                                                     \
  for (int c = 0; c < CH; c++) {                                        \
    int i_ = (I0) + c;                                                  \
    float gg_ = __shfl(__int_as_float(em.y), i_ & 15, 16);              \
    float gu_ = __shfl(guv, i_ & 15, 16);                               \
    if (i_ < cnt) {                                                     \
      float4 v0_ = lo4(Abuf[c]);                                        \
      float4 v1_ = hi4(Abuf[c]);                                        \
      float4 vy_ = lo4(Bbuf[c]);                                        \
      float4 xt_ = hi4(Bbuf[c]);                                        \
      float pq_ = fmaxf(xb1.x + xt_.x, 0.f) * w2v.x                     \
                + fmaxf(xb1.y + xt_.y, 0.f) * w2v.y                     \
                + fmaxf(xb1.z + xt_.z, 0.f) * w2v.z                     \
                + fmaxf(xb1.w + xt_.w, 0.f) * w2v.w;                    \
      pq_ += __shfl_xor(pq_, 1, 16);                                    \
      pq_ += __shfl_xor(pq_, 2, 16);                                    \
      pq_ += __shfl_xor(pq_, 4, 16);                                    \
      pq_ += __shfl_xor(pq_, 8, 16);                                    \
      float w_ = fsig(gu_ + pq_ + b2s);                                 \
      wsum += w_;                                                       \
      fma4(acc0, gg_, v0_);                                             \
      fma4(acc1, w_, v1_);                                              \
      fma4(acc2, gg_, vy_);                                             \
    }                                                                   \
  }

// OUTM: 0 = no out (L=2 layer0);  1 = out = emb0 + rc + en (L=2 final, nt stores,
//       dead-state writes skipped); 2 = out = rc + en; 3 = out += en
// GSEL: gumbel source — 0: em.z, 1: em.w, 2: cgum[]
template <int FIRST, int OUTM, int GSEL>
__global__ __launch_bounds__(256) void spmm3f_k(const int* __restrict__ rp,
    const int4* __restrict__ emeta, const float* __restrict__ cgum,
    const unsigned short* __restrict__ pk, const unsigned short* __restrict__ xhb,
    const unsigned short* __restrict__ e2b_in,
    const float* __restrict__ b1, const float* __restrict__ W2,
    const float* __restrict__ b2, const float* __restrict__ emb0,
    unsigned short* __restrict__ pkn, unsigned short* __restrict__ e2b,
    float* __restrict__ out0, float* __restrict__ out1, float* __restrict__ out2,
    int N, int B) {
  int g = threadIdx.x >> 4;
  int l = threadIdx.x & 15;
  int n = blockIdx.x * 16 + g;
  if (n >= N) return;
  int jb = rp[(size_t)n * B], je = rp[(size_t)(n + 1) * B];
  size_t o64 = (size_t)n * 64 + l * 4;
  float4 xh4 = ldbf4(xhb + o64);
  float4 b1v = *(const float4*)(b1 + l * 4);
  float4 xb1 = add4(xh4, b1v);
  float4 w2v = *(const float4*)(W2 + l * 4);
  float b2s = b2[0];
  float4 rc0, rc1, rc2;
  if (FIRST) {
    rc0 = *(const float4*)(emb0 + o64);
    rc1 = rc0; rc2 = rc0;
  } else {
    uint4 rA = *(const uint4*)(pk + (size_t)n * PK_STRIDE + l * 8);
    rc0 = lo4(rA);
    rc1 = hi4(rA);
    rc2 = ldbf4(e2b_in + o64);
  }
  float4 acc0 = f4z(), acc1 = f4z(), acc2 = f4z();
  float wsum = 0.f;
  for (int base = jb; base < je; base += 16) {
    int idx = base + l;
    bool valid = idx < je;
    int4 em = valid ? emeta[idx] : make_int4(0, 0, 0, 0);
    float guv;
    if (GSEL == 0) guv = __int_as_float(em.z);
    else if (GSEL == 1) guv = __int_as_float(em.w);
    else guv = valid ? cgum[idx] : 0.f;
    int cnt = min(16, je - base);
    uint4 A0[CH], B0[CH], A1[CH], B1[CH];
    LOADCH(A0, B0, 0)
    for (int i0 = 0; i0 < cnt; i0 += 2 * CH) {
      LOADCH(A1, B1, i0 + CH)
      COMPCH(A0, B0, i0)
      LOADCH(A0, B0, i0 + 2 * CH)
      COMPCH(A1, B1, i0 + CH)
    }
  }
  float dinv = (wsum > 0.f) ? __builtin_amdgcn_rcpf(wsum) : 0.f;
  float4 en0 = add4(acc0, rc0);
  acc1.x *= dinv; acc1.y *= dinv; acc1.z *= dinv; acc1.w *= dinv;
  float4 en1 = add4(acc1, rc1);
  float4 en2 = add4(acc2, rc2);
  if (OUTM != 1) {     // final layer: state is dead, skip writes
    uint4 wA;
    wA.x = pack2(en0.x, en0.y); wA.y = pack2(en0.z, en0.w);
    wA.z = pack2(en1.x, en1.y); wA.w = pack2(en1.z, en1.w);
    *(uint4*)(pkn + (size_t)n * PK_STRIDE + l * 8) = wA;
    st4bf(e2b + o64, en2);
  }
  if (OUTM == 1) {
    float4 base = *(const float4*)(emb0 + o64);
    stnt4(out0 + o64, add4(base, add4(rc0, en0)));
    stnt4(out1 + o64, add4(base, add4(rc1, en1)));
    stnt4(out2 + o64, add4(base, add4(rc2, en2)));
  } else if (OUTM == 2) {
    *(float4*)(out0 + o64) = add4(rc0, en0);
    *(float4*)(out1 + o64) = add4(rc1, en1);
    *(float4*)(out2 + o64) = add4(rc2, en2);
  } else if (OUTM == 3) {
    *(float4*)(out0 + o64) = add4(*(const float4*)(out0 + o64), en0);
    *(float4*)(out1 + o64) = add4(*(const float4*)(out1 + o64), en1);
    *(float4*)(out2 + o64) = add4(*(const float4*)(out2 + o64), en2);
  }
}

extern "C" void kernel_launch(void* const* d_in, const int* in_sizes, int n_in,
                              void* d_out, int out_size, void* d_ws, size_t ws_size,
                              hipStream_t stream) {
  const float* emb0        = (const float*)d_in[0];
  const int*   h_idx       = (const int*)d_in[1];
  const int*   t_idx       = (const int*)d_in[2];
  const float* G_values    = (const float*)d_in[3];
  const float* edge_gumbel = (const float*)d_in[4];
  const float* emb_gumbel  = (const float*)d_in[5];
  const float* edge_W1     = (const float*)d_in[6];
  const float* edge_b1     = (const float*)d_in[7];
  const float* edge_W2     = (const float*)d_in[8];
  const float* edge_b2     = (const float*)d_in[9];
  const float* emb_W1      = (const float*)d_in[10];
  const float* emb_b1      = (const float*)d_in[11];
  const float* emb_W2      = (const float*)d_in[12];
  const float* emb_b2      = (const float*)d_in[13];

  const int D = 64;
  const int N = in_sizes[0] / D;
  const int E = in_sizes[1];
  const int L = in_sizes[4] / E;
  const size_t ND = (size_t)N * D;
  const int B = (N + (1 << TSHIFT) - 1) >> TSHIFT;   // t-buckets per row
  const size_t NB = (size_t)N * B;

  char* p = (char*)d_ws;
  auto alloc = [&](size_t bytes) -> char* {
    char* r = p;
    p += (bytes + 255) & ~(size_t)255;
    return r;
  };
  unsigned short* xhb = (unsigned short*)alloc(ND * 2);
  unsigned short* e2b = (unsigned short*)alloc(ND * 2);
  unsigned short* pkA = (unsigned short*)alloc((size_t)N * PK_STRIDE * 2);
  unsigned short* pkB = (unsigned short*)alloc((size_t)N * PK_STRIDE * 2);
  int4*  emeta = (int4*)alloc((size_t)E * 16);
  float* cgum  = (float*)alloc((L > 2 ? (size_t)L * E : 1) * 4);
  unsigned short* wxT = (unsigned short*)alloc((size_t)L * 8192 * 2);
  unsigned short* w1T = (unsigned short*)alloc((size_t)L * 4096 * 2);
  unsigned short* w2T = (unsigned short*)alloc((size_t)L * 4096 * 2);
  int*   deg   = (int*)alloc(NB * 4);
  int*   cur   = (int*)alloc(NB * 4);
  int*   rp    = (int*)alloc((NB + 1) * 4);
  int*   sums  = (int*)alloc(4096 * 4);

  float* out = (float*)d_out;

  init_k<<<(N * 16 + 255) / 256, 256, 0, stream>>>(emb0, pkA, e2b, N);
  hipMemsetAsync(deg, 0, NB * 4, stream);
  hist_k<<<(E + 255) / 256, 256, 0, stream>>>(h_idx, t_idx, deg, E, B);
  int nch = (int)((NB + 1023) / 1024);
  scanA_k<<<nch, 1024, 0, stream>>>(deg, rp, sums, (int)NB);
  scanB_k<<<1, 64, 0, stream>>>(sums, nch);
  scanC_k<<<(int)((NB + 256) / 256), 256, 0, stream>>>(rp, cur, sums, (int)NB, E);
  fill_k<<<(E + 255) / 256, 256, 0, stream>>>(h_idx, t_idx, G_values, edge_gumbel,
                                              cur, emeta, cgum, E, L, B);
  wprep_k<<<(L * 16384 + 255) / 256, 256, 0, stream>>>(edge_W1, emb_W1, emb_W2,
                                                       wxT, w1T, w2T, L);

  int nb64 = (N + 63) / 64;
  int nb16 = (N + 15) / 16;

  for (int i = 0; i < L; i++) {
    unsigned short* pkc = (i & 1) ? pkB : pkA;
    unsigned short* pkn = (i & 1) ? pkA : pkB;
    dense_k<<<nb64, 256, 0, stream>>>(pkc, e2b,
                                      wxT + (size_t)i * 8192,
                                      w1T + (size_t)i * 4096,
                                      w2T + (size_t)i * 4096,
                                      emb_b1 + (size_t)i * 64,
                                      emb_b2 + (size_t)i * 64,
                                      emb_gumbel + (size_t)i * ND,
                                      xhb, pkc, N);
    const float* cg = cgum;
    const float* eb1 = edge_b1 + (size_t)i * 64;
    const float* eW2 = edge_W2 + (size_t)i * 64;
    const float* eb2 = edge_b2 + i;
    if (L == 2) {
      if (i == 0)
        spmm3f_k<1, 0, 0><<<nb16, 256, 0, stream>>>(rp, emeta, cg, pkc, xhb, e2b,
                                                    eb1, eW2, eb2, emb0, pkn, e2b,
                                                    out, out + ND, out + 2 * ND, N, B);
      else
        spmm3f_k<0, 1, 1><<<nb16, 256, 0, stream>>>(rp, emeta, cg, pkc, xhb, e2b,
                                                    eb1, eW2, eb2, emb0, pkn, e2b,
                                                    out, out + ND, out + 2 * ND, N, B);
    } else {
      const float* cgl = cgum + (size_t)i * E;
      if (i == 0)
        spmm3f_k<1, 2, 0><<<nb16, 256, 0, stream>>>(rp, emeta, cgl, pkc, xhb, e2b,
                                                    eb1, eW2, eb2, emb0, pkn, e2b,
                                                    out, out + ND, out + 2 * ND, N, B);
      else if (i == 1)
        spmm3f_k<0, 3, 1><<<nb16, 256, 0, stream>>>(rp, emeta, cgl, pkc, xhb, e2b,
                                                    eb1, eW2, eb2, emb0, pkn, e2b,
                                                    out, out + ND, out + 2 * ND, N, B);
      else
        spmm3f_k<0, 3, 2><<<nb16, 256, 0, stream>>>(rp, emeta, cgl, pkc, xhb, e2b,
                                                    eb1, eW2, eb2, emb0, pkn, e2b,
                                                    out, out + ND, out + 2 * ND, N, B);
    }
  }
}

// Round 11
// 331.396 us; speedup vs baseline: 1.0967x; 1.0967x over previous
//
#include <hip/hip_runtime.h>
#include <hip/hip_bf16.h>
#include <math.h>

// pk row: 256 bf16 = 512B, line-aligned.
//   elems 0..127  : E0E1 region, chunk c (0..15) = [e0[4c..4c+3] | e1[4c..4c+3]]
//   elems 128..255: Y2XT region, chunk c = [y2 quad | xt quad]
// e2 lives in a separate dense e2b[N][64]; emb0b is a dense bf16 copy of emb0.
#define PK_STRIDE 256
#define LDA 72   // LDS row stride (bf16 elems): 144B, 16B-aligned, 2-way alias only

typedef float v4f __attribute__((ext_vector_type(4)));
typedef __attribute__((ext_vector_type(8))) short s8;
typedef __attribute__((ext_vector_type(4))) float f4;

__device__ __forceinline__ float4 f4z() { return make_float4(0.f, 0.f, 0.f, 0.f); }
__device__ __forceinline__ void fma4(float4& a, float s, const float4& v) {
  a.x = fmaf(s, v.x, a.x); a.y = fmaf(s, v.y, a.y);
  a.z = fmaf(s, v.z, a.z); a.w = fmaf(s, v.w, a.w);
}
__device__ __forceinline__ float4 add4(const float4& a, const float4& b) {
  return make_float4(a.x + b.x, a.y + b.y, a.z + b.z, a.w + b.w);
}
__device__ __forceinline__ void stnt4(float* p, const float4& v) {
  v4f u; u.x = v.x; u.y = v.y; u.z = v.z; u.w = v.w;
  __builtin_nontemporal_store(u, (v4f*)p);
}
__device__ __forceinline__ float4 lo4(const uint4& u) {
  float4 f;
  f.x = __uint_as_float(u.x << 16);
  f.y = __uint_as_float(u.x & 0xffff0000u);
  f.z = __uint_as_float(u.y << 16);
  f.w = __uint_as_float(u.y & 0xffff0000u);
  return f;
}
__device__ __forceinline__ float4 hi4(const uint4& u) {
  float4 f;
  f.x = __uint_as_float(u.z << 16);
  f.y = __uint_as_float(u.z & 0xffff0000u);
  f.z = __uint_as_float(u.w << 16);
  f.w = __uint_as_float(u.w & 0xffff0000u);
  return f;
}
__device__ __forceinline__ float4 cvt2(const uint2& u) {   // 4 packed bf16 -> f32x4
  float4 f;
  f.x = __uint_as_float(u.x << 16);
  f.y = __uint_as_float(u.x & 0xffff0000u);
  f.z = __uint_as_float(u.y << 16);
  f.w = __uint_as_float(u.y & 0xffff0000u);
  return f;
}
__device__ __forceinline__ float4 ldbf4(const unsigned short* p) {
  ushort4 u = *(const ushort4*)p;
  float4 f;
  f.x = __uint_as_float((unsigned)u.x << 16);
  f.y = __uint_as_float((unsigned)u.y << 16);
  f.z = __uint_as_float((unsigned)u.z << 16);
  f.w = __uint_as_float((unsigned)u.w << 16);
  return f;
}
__device__ __forceinline__ unsigned short f2bf(float v) {
  __hip_bfloat16 h = __float2bfloat16(v);
  return *reinterpret_cast<unsigned short*>(&h);
}
__device__ __forceinline__ unsigned pack2(float a, float b) {
  return ((unsigned)f2bf(b) << 16) | (unsigned)f2bf(a);
}
__device__ __forceinline__ void st4bf(unsigned short* p, const float4& v) {
  ushort4 u;
  u.x = f2bf(v.x); u.y = f2bf(v.y); u.z = f2bf(v.z); u.w = f2bf(v.w);
  *(ushort4*)p = u;
}
__device__ __forceinline__ float fsig(float x) {
  return __builtin_amdgcn_rcpf(1.f + __expf(-x));
}

// ---------------- CSR build ----------------
__global__ void hist_k(const int* __restrict__ h, int* __restrict__ deg, int E) {
  int i = blockIdx.x * blockDim.x + threadIdx.x;
  if (i < E) atomicAdd(&deg[h[i]], 1);
}

__global__ void scanA_k(const int* __restrict__ deg, int* __restrict__ rp,
                        int* __restrict__ sums, int N) {
  __shared__ int s[1024];
  int i = blockIdx.x * 1024 + threadIdx.x;
  int v = (i < N) ? deg[i] : 0;
  s[threadIdx.x] = v;
  __syncthreads();
  for (int off = 1; off < 1024; off <<= 1) {
    int t = (threadIdx.x >= (unsigned)off) ? s[threadIdx.x - off] : 0;
    __syncthreads();
    s[threadIdx.x] += t;
    __syncthreads();
  }
  if (i < N) rp[i] = s[threadIdx.x] - v;
  if (threadIdx.x == 1023) sums[blockIdx.x] = s[1023];
}

__global__ void scanB_k(int* sums, int nch) {
  int lane = threadIdx.x;   // 64 threads
  int run = 0;
  for (int base = 0; base < nch; base += 64) {
    int v = (base + lane < nch) ? sums[base + lane] : 0;
    int incl = v;
    for (int off = 1; off < 64; off <<= 1) {
      int t = __shfl_up(incl, off, 64);
      if (lane >= off) incl += t;
    }
    if (base + lane < nch) sums[base + lane] = run + (incl - v);
    run += __shfl(incl, 63, 64);
  }
}

__global__ void scanC_k(int* __restrict__ rp, int* __restrict__ cur,
                        const int* __restrict__ sums, int N, int E) {
  int i = blockIdx.x * blockDim.x + threadIdx.x;
  if (i < N) {
    int v = rp[i] + sums[i >> 10];
    rp[i] = v; cur[i] = v;
  } else if (i == N) {
    rp[N] = E;
  }
}

// fill: one 16B emeta write per edge {toff, G, gum_l0, gum_l1}; cgum only if L>2
__global__ void fill_k(const int* __restrict__ h, const int* __restrict__ t_idx,
                       const float* __restrict__ G, const float* __restrict__ gum,
                       int* __restrict__ cur, int4* __restrict__ emeta,
                       float* __restrict__ cgum, int E, int L) {
  int i = blockIdx.x * blockDim.x + threadIdx.x;
  if (i < E) {
    int pos = atomicAdd(&cur[h[i]], 1);
    int4 em;
    em.x = t_idx[i] * PK_STRIDE;
    em.y = __float_as_int(G[i]);
    em.z = __float_as_int(gum[i]);
    em.w = (L > 1) ? __float_as_int(gum[(size_t)E + i]) : 0;
    emeta[pos] = em;
    if (L > 2)
      for (int l = 2; l < L; l++) cgum[(size_t)l * E + pos] = gum[(size_t)l * E + i];
  }
}

// ------- weight prep: transpose + bf16 once -------
__global__ void wprep_k(const float* __restrict__ edge_W1,
                        const float* __restrict__ emb_W1,
                        const float* __restrict__ emb_W2,
                        unsigned short* __restrict__ wxT,
                        unsigned short* __restrict__ w1T,
                        unsigned short* __restrict__ w2T, int L) {
  const int per = 128 * 64 + 64 * 64 + 64 * 64;   // 16384
  int i = blockIdx.x * blockDim.x + threadIdx.x;
  if (i >= L * per) return;
  int layer = i / per, r = i % per;
  if (r < 8192) {
    int j = r >> 6, k = r & 63;
    float v = (j < 64) ? edge_W1[((size_t)layer * 128 + k) * 64 + j]
                       : edge_W1[((size_t)layer * 128 + 64 + k) * 64 + (j - 64)];
    wxT[(size_t)layer * 8192 + j * 64 + k] = f2bf(v);
  } else if (r < 8192 + 4096) {
    int q = r - 8192; int n = q >> 6, k = q & 63;
    w1T[(size_t)layer * 4096 + n * 64 + k] =
        f2bf(emb_W1[((size_t)layer * 64 + k) * 64 + n]);
  } else {
    int q = r - 12288; int n = q >> 6, k = q & 63;
    w2T[(size_t)layer * 4096 + n * 64 + k] =
        f2bf(emb_W2[((size_t)layer * 64 + k) * 64 + n]);
  }
}

// ------- fused dense layer (MFMA) -------
// FIRST=1: e1=e2=emb0 (fp32 in); also emits emb0b (bf16 copy) for spmm L0 gather.
template <int FIRST>
__global__ __launch_bounds__(256) void dense_k(
    const float* __restrict__ emb0,
    const unsigned short* __restrict__ pkin,   // e1 source (E0E1 hi quads), !FIRST
    const unsigned short* __restrict__ e2b,    // e2 source, !FIRST
    const unsigned short* __restrict__ wxT,    // [128][64] bf16
    const unsigned short* __restrict__ w1T,    // [64][64]
    const unsigned short* __restrict__ w2T,    // [64][64]
    const float* __restrict__ b1,
    const float* __restrict__ b2,
    const float* __restrict__ gum,
    unsigned short* __restrict__ xhb,
    unsigned short* __restrict__ pk,           // Y2XT writes
    unsigned short* __restrict__ emb0b,        // FIRST only
    int N) {
  __shared__ unsigned short a1[64 * LDA];      // e1, reused as ht
  __shared__ unsigned short a2[64 * LDA];      // e2
  __shared__ unsigned short wx[128 * LDA];
  __shared__ unsigned short w1[64 * LDA];
  __shared__ unsigned short w2[64 * LDA];
  int tid = threadIdx.x;
  int n0 = blockIdx.x * 64;
  if (FIRST) {
    for (int i = tid; i < 64 * 8; i += 256) {
      int r = i >> 3, c8 = (i & 7) * 8;
      uint4 u = make_uint4(0, 0, 0, 0);
      if (n0 + r < N) {
        const float* src = emb0 + (size_t)(n0 + r) * 64 + c8;
        float4 lo = *(const float4*)src;
        float4 hi = *(const float4*)(src + 4);
        u.x = pack2(lo.x, lo.y); u.y = pack2(lo.z, lo.w);
        u.z = pack2(hi.x, hi.y); u.w = pack2(hi.z, hi.w);
        *(uint4*)(emb0b + (size_t)(n0 + r) * 64 + c8) = u;
      }
      *(uint4*)(a1 + r * LDA + c8) = u;
      *(uint4*)(a2 + r * LDA + c8) = u;
    }
  } else {
    for (int i = tid; i < 64 * 16; i += 256) {
      int r = i >> 4, c = i & 15;
      ushort4 v1 = make_ushort4(0, 0, 0, 0), v2 = v1;
      if (n0 + r < N) {
        v1 = *(const ushort4*)(pkin + (size_t)(n0 + r) * PK_STRIDE + c * 8 + 4);
        v2 = *(const ushort4*)(e2b + (size_t)(n0 + r) * 64 + c * 4);
      }
      *(ushort4*)(a1 + r * LDA + c * 4) = v1;
      *(ushort4*)(a2 + r * LDA + c * 4) = v2;
    }
  }
  for (int i = tid; i < 128 * 8; i += 256) {
    int r = i >> 3, s = i & 7;
    *(uint4*)(wx + r * LDA + s * 8) = *(const uint4*)(wxT + r * 64 + s * 8);
  }
  for (int i = tid; i < 64 * 8; i += 256) {
    int r = i >> 3, s = i & 7;
    *(uint4*)(w1 + r * LDA + s * 8) = *(const uint4*)(w1T + r * 64 + s * 8);
    *(uint4*)(w2 + r * LDA + s * 8) = *(const uint4*)(w2T + r * 64 + s * 8);
  }
  __syncthreads();
  int wv = tid >> 6, l = tid & 63;
  int l15 = l & 15, lg = l >> 4;
  int wr = wv * 16;
  int arow = wr + l15;
  s8 af1_0 = *(const s8*)(a1 + arow * LDA + 8 * lg);
  s8 af1_1 = *(const s8*)(a1 + arow * LDA + 32 + 8 * lg);
#pragma unroll
  for (int ct = 0; ct < 8; ct++) {
    f4 acc = {0.f, 0.f, 0.f, 0.f};
    s8 b0 = *(const s8*)(wx + (ct * 16 + l15) * LDA + 8 * lg);
    s8 bI = *(const s8*)(wx + (ct * 16 + l15) * LDA + 32 + 8 * lg);
    acc = __builtin_amdgcn_mfma_f32_16x16x32_bf16(af1_0, b0, acc, 0, 0, 0);
    acc = __builtin_amdgcn_mfma_f32_16x16x32_bf16(af1_1, bI, acc, 0, 0, 0);
#pragma unroll
    for (int j = 0; j < 4; j++) {
      int n = n0 + wr + lg * 4 + j;
      if (n < N) {
        if (ct < 4) {
          xhb[(size_t)n * 64 + ct * 16 + l15] = f2bf(acc[j]);
        } else {
          int c2 = (ct - 4) * 16 + l15;
          pk[(size_t)n * PK_STRIDE + 128 + (c2 >> 2) * 8 + 4 + (c2 & 3)] = f2bf(acc[j]);
        }
      }
    }
  }
  s8 af2_0 = *(const s8*)(a2 + arow * LDA + 8 * lg);
  s8 af2_1 = *(const s8*)(a2 + arow * LDA + 32 + 8 * lg);
#pragma unroll
  for (int ct = 0; ct < 4; ct++) {
    f4 acc = {0.f, 0.f, 0.f, 0.f};
    s8 b0 = *(const s8*)(w1 + (ct * 16 + l15) * LDA + 8 * lg);
    s8 bI = *(const s8*)(w1 + (ct * 16 + l15) * LDA + 32 + 8 * lg);
    acc = __builtin_amdgcn_mfma_f32_16x16x32_bf16(af2_0, b0, acc, 0, 0, 0);
    acc = __builtin_amdgcn_mfma_f32_16x16x32_bf16(af2_1, bI, acc, 0, 0, 0);
    float bb = b1[ct * 16 + l15];
#pragma unroll
    for (int j = 0; j < 4; j++) {
      float h = fmaxf(acc[j] + bb, 0.f);
      a1[(wr + lg * 4 + j) * LDA + ct * 16 + l15] = f2bf(h);
    }
  }
  s8 afh_0 = *(const s8*)(a1 + arow * LDA + 8 * lg);
  s8 afh_1 = *(const s8*)(a1 + arow * LDA + 32 + 8 * lg);
#pragma unroll
  for (int ct = 0; ct < 4; ct++) {
    f4 acc = {0.f, 0.f, 0.f, 0.f};
    s8 b0 = *(const s8*)(w2 + (ct * 16 + l15) * LDA + 8 * lg);
    s8 bI = *(const s8*)(w2 + (ct * 16 + l15) * LDA + 32 + 8 * lg);
    acc = __builtin_amdgcn_mfma_f32_16x16x32_bf16(afh_0, b0, acc, 0, 0, 0);
    acc = __builtin_amdgcn_mfma_f32_16x16x32_bf16(afh_1, bI, acc, 0, 0, 0);
    int c2 = ct * 16 + l15;
    float bb = b2[c2];
#pragma unroll
    for (int j = 0; j < 4; j++) {
      int row = wr + lg * 4 + j;
      int n = n0 + row;
      if (n < N) {
        float gv = gum[(size_t)n * 64 + c2];
        float e2v = __uint_as_float((unsigned)a2[row * LDA + c2] << 16);
        float y = e2v * fsig(gv + acc[j] + bb);
        pk[(size_t)n * PK_STRIDE + 128 + (c2 >> 2) * 8 + (c2 & 3)] = f2bf(y);
      }
    }
  }
}

// ------- fused 3-branch SpMM + edge-MLP + dinv + residual + out -------
#define CH 2

// non-FIRST: A (16B) from pk E0E1, B (16B) from pk Y2XT
#define LOADCH(Abuf, Bbuf, I0)                                          \
  _Pragma("unroll")                                                     \
  for (int c = 0; c < CH; c++) {                                        \
    int i_ = (I0) + c;                                                  \
    int tof_ = __shfl(em.x, i_ & 15, 16);                               \
    if (i_ < cnt) {                                                     \
      const unsigned short* pr_ = pk + (size_t)tof_ + l * 8;            \
      Abuf[c] = *(const uint4*)(pr_);                                   \
      Bbuf[c] = *(const uint4*)(pr_ + 128);                             \
    }                                                                   \
  }

#define COMPCH(Abuf, Bbuf, I0)                                          \
  _Pragma("unroll")                                                     \
  for (int c = 0; c < CH; c++) {                                        \
    int i_ = (I0) + c;                                                  \
    float gg_ = __shfl(__int_as_float(em.y), i_ & 15, 16);              \
    float gu_ = __shfl(guv, i_ & 15, 16);                               \
    if (i_ < cnt) {                                                     \
      float4 v0_ = lo4(Abuf[c]);                                        \
      float4 v1_ = hi4(Abuf[c]);                                        \
      float4 vy_ = lo4(Bbuf[c]);                                        \
      float4 xt_ = hi4(Bbuf[c]);                                        \
      float pq_ = fmaxf(xb1.x + xt_.x, 0.f) * w2v.x                     \
                + fmaxf(xb1.y + xt_.y, 0.f) * w2v.y                     \
                + fmaxf(xb1.z + xt_.z, 0.f) * w2v.z                     \
                + fmaxf(xb1.w + xt_.w, 0.f) * w2v.w;                    \
      pq_ += __shfl_xor(pq_, 1, 16);                                    \
      pq_ += __shfl_xor(pq_, 2, 16);                                    \
      pq_ += __shfl_xor(pq_, 4, 16);                                    \
      pq_ += __shfl_xor(pq_, 8, 16);                                    \
      float w_ = fsig(gu_ + pq_ + b2s);                                 \
      wsum += w_;                                                       \
      fma4(acc0, gg_, v0_);                                             \
      fma4(acc1, w_, v1_);                                              \
      fma4(acc2, gg_, vy_);                                             \
    }                                                                   \
  }

// FIRST: A (8B, v0=v1) from emb0b, B (16B) from pk Y2XT
#define LOADCH_F(Abuf, Bbuf, I0)                                        \
  _Pragma("unroll")                                                     \
  for (int c = 0; c < CH; c++) {                                        \
    int i_ = (I0) + c;                                                  \
    int tof_ = __shfl(em.x, i_ & 15, 16);                               \
    if (i_ < cnt) {                                                     \
      Abuf[c] = *(const uint2*)(emb0b + (size_t)(tof_ >> 2) + l * 4);   \
      Bbuf[c] = *(const uint4*)(pk + (size_t)tof_ + 128 + l * 8);       \
    }                                                                   \
  }

#define COMPCH_F(Abuf, Bbuf, I0)                                        \
  _Pragma("unroll")                                                     \
  for (int c = 0; c < CH; c++) {                                        \
    int i_ = (I0) + c;                                                  \
    float gg_ = __shfl(__int_as_float(em.y), i_ & 15, 16);              \
    float gu_ = __shfl(guv, i_ & 15, 16);                               \
    if (i_ < cnt) {                                                     \
      float4 v0_ = cvt2(Abuf[c]);                                       \
      float4 vy_ = lo4(Bbuf[c]);                                        \
      float4 xt_ = hi4(Bbuf[c]);                                        \
      float pq_ = fmaxf(xb1.x + xt_.x, 0.f) * w2v.x                     \
                + fmaxf(xb1.y + xt_.y, 0.f) * w2v.y                     \
                + fmaxf(xb1.z + xt_.z, 0.f) * w2v.z                     \
                + fmaxf(xb1.w + xt_.w, 0.f) * w2v.w;                    \
      pq_ += __shfl_xor(pq_, 1, 16);                                    \
      pq_ += __shfl_xor(pq_, 2, 16);                                    \
      pq_ += __shfl_xor(pq_, 4, 16);                                    \
      pq_ += __shfl_xor(pq_, 8, 16);                                    \
      float w_ = fsig(gu_ + pq_ + b2s);                                 \
      wsum += w_;                                                       \
      fma4(acc0, gg_, v0_);                                             \
      fma4(acc1, w_, v0_);                                              \
      fma4(acc2, gg_, vy_);                                             \
    }                                                                   \
  }

// OUTM: 0 = no out (L=2 layer0);  1 = out = emb0 + rc + en (L=2 final, nt stores,
//       dead-state writes skipped); 2 = out = rc + en; 3 = out += en
// GSEL: gumbel source — 0: em.z, 1: em.w, 2: cgum[]
template <int FIRST, int OUTM, int GSEL>
__global__ __launch_bounds__(256) void spmm3f_k(const int* __restrict__ rp,
    const int4* __restrict__ emeta, const float* __restrict__ cgum,
    const unsigned short* __restrict__ pk, const unsigned short* __restrict__ xhb,
    const unsigned short* __restrict__ e2b_in,
    const unsigned short* __restrict__ emb0b,
    const float* __restrict__ b1, const float* __restrict__ W2,
    const float* __restrict__ b2, const float* __restrict__ emb0,
    unsigned short* __restrict__ pkn, unsigned short* __restrict__ e2b,
    float* __restrict__ out0, float* __restrict__ out1, float* __restrict__ out2,
    int N) {
  int g = threadIdx.x >> 4;
  int l = threadIdx.x & 15;
  int n = blockIdx.x * 16 + g;
  if (n >= N) return;
  int jb = rp[n], je = rp[n + 1];
  size_t o64 = (size_t)n * 64 + l * 4;
  float4 xh4 = ldbf4(xhb + o64);
  float4 b1v = *(const float4*)(b1 + l * 4);
  float4 xb1 = add4(xh4, b1v);
  float4 w2v = *(const float4*)(W2 + l * 4);
  float b2s = b2[0];
  float4 rc0, rc1, rc2;
  if (FIRST) {
    rc0 = *(const float4*)(emb0 + o64);
    rc1 = rc0; rc2 = rc0;
  } else {
    uint4 rA = *(const uint4*)(pk + (size_t)n * PK_STRIDE + l * 8);
    rc0 = lo4(rA);
    rc1 = hi4(rA);
    rc2 = ldbf4(e2b_in + o64);
  }
  float4 acc0 = f4z(), acc1 = f4z(), acc2 = f4z();
  float wsum = 0.f;
  for (int base = jb; base < je; base += 16) {
    int idx = base + l;
    bool valid = idx < je;
    int4 em = valid ? emeta[idx] : make_int4(0, 0, 0, 0);
    float guv;
    if (GSEL == 0) guv = __int_as_float(em.z);
    else if (GSEL == 1) guv = __int_as_float(em.w);
    else guv = valid ? cgum[idx] : 0.f;
    int cnt = min(16, je - base);
    if (FIRST) {
      uint2 A0[CH], A1[CH];
      uint4 B0[CH], B1[CH];
      LOADCH_F(A0, B0, 0)
      for (int i0 = 0; i0 < cnt; i0 += 2 * CH) {
        LOADCH_F(A1, B1, i0 + CH)
        COMPCH_F(A0, B0, i0)
        LOADCH_F(A0, B0, i0 + 2 * CH)
        COMPCH_F(A1, B1, i0 + CH)
      }
    } else {
      uint4 A0[CH], B0[CH], A1[CH], B1[CH];
      LOADCH(A0, B0, 0)
      for (int i0 = 0; i0 < cnt; i0 += 2 * CH) {
        LOADCH(A1, B1, i0 + CH)
        COMPCH(A0, B0, i0)
        LOADCH(A0, B0, i0 + 2 * CH)
        COMPCH(A1, B1, i0 + CH)
      }
    }
  }
  float dinv = (wsum > 0.f) ? __builtin_amdgcn_rcpf(wsum) : 0.f;
  float4 en0 = add4(acc0, rc0);
  acc1.x *= dinv; acc1.y *= dinv; acc1.z *= dinv; acc1.w *= dinv;
  float4 en1 = add4(acc1, rc1);
  float4 en2 = add4(acc2, rc2);
  if (OUTM != 1) {     // final layer: state is dead, skip writes
    uint4 wA;
    wA.x = pack2(en0.x, en0.y); wA.y = pack2(en0.z, en0.w);
    wA.z = pack2(en1.x, en1.y); wA.w = pack2(en1.z, en1.w);
    *(uint4*)(pkn + (size_t)n * PK_STRIDE + l * 8) = wA;
    st4bf(e2b + o64, en2);
  }
  if (OUTM == 1) {
    float4 base = *(const float4*)(emb0 + o64);
    stnt4(out0 + o64, add4(base, add4(rc0, en0)));
    stnt4(out1 + o64, add4(base, add4(rc1, en1)));
    stnt4(out2 + o64, add4(base, add4(rc2, en2)));
  } else if (OUTM == 2) {
    *(float4*)(out0 + o64) = add4(rc0, en0);
    *(float4*)(out1 + o64) = add4(rc1, en1);
    *(float4*)(out2 + o64) = add4(rc2, en2);
  } else if (OUTM == 3) {
    *(float4*)(out0 + o64) = add4(*(const float4*)(out0 + o64), en0);
    *(float4*)(out1 + o64) = add4(*(const float4*)(out1 + o64), en1);
    *(float4*)(out2 + o64) = add4(*(const float4*)(out2 + o64), en2);
  }
}

extern "C" void kernel_launch(void* const* d_in, const int* in_sizes, int n_in,
                              void* d_out, int out_size, void* d_ws, size_t ws_size,
                              hipStream_t stream) {
  const float* emb0        = (const float*)d_in[0];
  const int*   h_idx       = (const int*)d_in[1];
  const int*   t_idx       = (const int*)d_in[2];
  const float* G_values    = (const float*)d_in[3];
  const float* edge_gumbel = (const float*)d_in[4];
  const float* emb_gumbel  = (const float*)d_in[5];
  const float* edge_W1     = (const float*)d_in[6];
  const float* edge_b1     = (const float*)d_in[7];
  const float* edge_W2     = (const float*)d_in[8];
  const float* edge_b2     = (const float*)d_in[9];
  const float* emb_W1      = (const float*)d_in[10];
  const float* emb_b1      = (const float*)d_in[11];
  const float* emb_W2      = (const float*)d_in[12];
  const float* emb_b2      = (const float*)d_in[13];

  const int D = 64;
  const int N = in_sizes[0] / D;
  const int E = in_sizes[1];
  const int L = in_sizes[4] / E;
  const size_t ND = (size_t)N * D;

  char* p = (char*)d_ws;
  auto alloc = [&](size_t bytes) -> char* {
    char* r = p;
    p += (bytes + 255) & ~(size_t)255;
    return r;
  };
  unsigned short* xhb   = (unsigned short*)alloc(ND * 2);
  unsigned short* e2b   = (unsigned short*)alloc(ND * 2);
  unsigned short* emb0b = (unsigned short*)alloc(ND * 2);
  unsigned short* pkA   = (unsigned short*)alloc((size_t)N * PK_STRIDE * 2);
  unsigned short* pkB   = (unsigned short*)alloc((size_t)N * PK_STRIDE * 2);
  int4*  emeta = (int4*)alloc((size_t)E * 16);
  float* cgum  = (float*)alloc((L > 2 ? (size_t)L * E : 1) * 4);
  unsigned short* wxT = (unsigned short*)alloc((size_t)L * 8192 * 2);
  unsigned short* w1T = (unsigned short*)alloc((size_t)L * 4096 * 2);
  unsigned short* w2T = (unsigned short*)alloc((size_t)L * 4096 * 2);
  int*   deg   = (int*)alloc((size_t)N * 4);
  int*   cur   = (int*)alloc((size_t)N * 4);
  int*   rp    = (int*)alloc(((size_t)N + 1) * 4);
  int*   sums  = (int*)alloc(1024 * 4);

  float* out = (float*)d_out;

  hipMemsetAsync(deg, 0, (size_t)N * 4, stream);
  hist_k<<<(E + 255) / 256, 256, 0, stream>>>(h_idx, deg, E);
  int nch = (N + 1023) / 1024;
  scanA_k<<<nch, 1024, 0, stream>>>(deg, rp, sums, N);
  scanB_k<<<1, 64, 0, stream>>>(sums, nch);
  scanC_k<<<(N + 256) / 256, 256, 0, stream>>>(rp, cur, sums, N, E);
  fill_k<<<(E + 255) / 256, 256, 0, stream>>>(h_idx, t_idx, G_values, edge_gumbel,
                                              cur, emeta, cgum, E, L);
  wprep_k<<<(L * 16384 + 255) / 256, 256, 0, stream>>>(edge_W1, emb_W1, emb_W2,
                                                       wxT, w1T, w2T, L);

  int nb64 = (N + 63) / 64;
  int nb16 = (N + 15) / 16;

  for (int i = 0; i < L; i++) {
    unsigned short* pkc = (i & 1) ? pkB : pkA;
    unsigned short* pkn = (i & 1) ? pkA : pkB;
    if (i == 0)
      dense_k<1><<<nb64, 256, 0, stream>>>(emb0, pkc, e2b,
                                           wxT, w1T, w2T,
                                           emb_b1, emb_b2, emb_gumbel,
                                           xhb, pkc, emb0b, N);
    else
      dense_k<0><<<nb64, 256, 0, stream>>>(emb0, pkc, e2b,
                                           wxT + (size_t)i * 8192,
                                           w1T + (size_t)i * 4096,
                                           w2T + (size_t)i * 4096,
                                           emb_b1 + (size_t)i * 64,
                                           emb_b2 + (size_t)i * 64,
                                           emb_gumbel + (size_t)i * ND,
                                           xhb, pkc, emb0b, N);
    const float* eb1 = edge_b1 + (size_t)i * 64;
    const float* eW2 = edge_W2 + (size_t)i * 64;
    const float* eb2 = edge_b2 + i;
    if (L == 2) {
      if (i == 0)
        spmm3f_k<1, 0, 0><<<nb16, 256, 0, stream>>>(rp, emeta, cgum, pkc, xhb, e2b,
                                                    emb0b, eb1, eW2, eb2, emb0,
                                                    pkn, e2b,
                                                    out, out + ND, out + 2 * ND, N);
      else
        spmm3f_k<0, 1, 1><<<nb16, 256, 0, stream>>>(rp, emeta, cgum, pkc, xhb, e2b,
                                                    emb0b, eb1, eW2, eb2, emb0,
                                                    pkn, e2b,
                                                    out, out + ND, out + 2 * ND, N);
    } else {
      const float* cgl = (L > 2) ? cgum + (size_t)i * E : cgum;
      if (i == 0)
        spmm3f_k<1, 2, 0><<<nb16, 256, 0, stream>>>(rp, emeta, cgl, pkc, xhb, e2b,
                                                    emb0b, eb1, eW2, eb2, emb0,
                                                    pkn, e2b,
                                                    out, out + ND, out + 2 * ND, N);
      else if (i == 1)
        spmm3f_k<0, 3, 1><<<nb16, 256, 0, stream>>>(rp, emeta, cgl, pkc, xhb, e2b,
                                                    emb0b, eb1, eW2, eb2, emb0,
                                                    pkn, e2b,
                                                    out, out + ND, out + 2 * ND, N);
      else
        spmm3f_k<0, 3, 2><<<nb16, 256, 0, stream>>>(rp, emeta, cgl, pkc, xhb, e2b,
                                                    emb0b, eb1, eW2, eb2, emb0,
                                                    pkn, e2b,
                                                    out, out + ND, out + 2 * ND, N);
    }
  }
}